// Round 1
// baseline (11724.625 us; speedup 1.0000x reference)
//
#include <hip/hip_runtime.h>

// ---------------------------------------------------------------- constants
namespace {
constexpr int   B_   = 16;
constexpr int   N_   = 20000;
constexpr int   C_   = 64;
constexpr int   DIM_ = 128;
constexpr int   K_   = 3;
constexpr int   E_   = 640000;
constexpr int   NB_  = 3;
constexpr int   ROW_ = B_ * C_;      // 1024 floats per node row in [N,B,C]
constexpr int   NR_  = N_ * B_;      // 320000 (n*B+b) rows of C floats

constexpr int   TM_  = 32;           // rows per MLP workgroup
constexpr int   LDA_ = 196;          // LDS stride for input/g2 tile (196%32=4 -> conflict-free, %4==0 -> float4 ok)
constexpr int   LDG_ = 132;          // LDS stride for g1 tile

// workspace layout (bytes)
constexpr size_t SZH_     = (size_t)N_ * B_ * C_ * sizeof(float);   // 81,920,000
constexpr size_t OFF_H    = 0;
constexpr size_t OFF_T1   = SZH_;
constexpr size_t OFF_S    = 2 * SZH_;
constexpr size_t OFF_DEG  = 3 * SZH_;
constexpr size_t OFF_CNT  = OFF_DEG + (size_t)N_ * 4;
constexpr size_t OFF_OFFS = OFF_CNT + (size_t)N_ * 4;
constexpr size_t OFF_COL  = ((OFF_OFFS + (size_t)(N_ + 1) * 4 + 255) / 256) * 256;
constexpr size_t OFF_VAL  = OFF_COL + (size_t)E_ * 4;
constexpr size_t OFF_WC   = OFF_VAL + (size_t)E_ * 4;
// total ~251.3 MB
} // namespace

// ---------------------------------------------------------------- graph prep
__global__ void deg_cnt_k(const int* __restrict__ src, const int* __restrict__ dst,
                          const float* __restrict__ ew,
                          float* __restrict__ deg, int* __restrict__ cnt) {
    int e = blockIdx.x * 256 + threadIdx.x;
    if (e < E_) {
        atomicAdd(deg + src[e], ew[e]);
        atomicAdd(cnt + dst[e], 1);
    }
}

__global__ void dinv_k(float* __restrict__ deg) {
    int i = blockIdx.x * 256 + threadIdx.x;
    if (i < N_) {
        float d = deg[i];
        deg[i] = (d > 0.f) ? rsqrtf(fmaxf(d, 1e-12f)) : 0.f;
    }
}

__global__ __launch_bounds__(1024) void scan_k(const int* __restrict__ cnt,
                                               int* __restrict__ offs) {
    __shared__ int sums[1024];
    const int tid = threadIdx.x;
    constexpr int CH = (N_ + 1023) / 1024;   // 20
    const int base = tid * CH;
    int local = 0;
    for (int j = 0; j < CH; ++j) {
        int i = base + j;
        if (i < N_) local += cnt[i];
    }
    sums[tid] = local;
    __syncthreads();
    for (int off = 1; off < 1024; off <<= 1) {
        int v = sums[tid];
        int u = (tid >= off) ? sums[tid - off] : 0;
        __syncthreads();
        sums[tid] = v + u;
        __syncthreads();
    }
    int run = (tid > 0) ? sums[tid - 1] : 0;
    for (int j = 0; j < CH; ++j) {
        int i = base + j;
        if (i < N_) { offs[i] = run; run += cnt[i]; }
    }
    if (tid == 1023) offs[N_] = sums[1023];
}

__global__ void scatter_k(const int* __restrict__ src, const int* __restrict__ dst,
                          const float* __restrict__ ew, const float* __restrict__ dinv,
                          const int* __restrict__ offs, int* __restrict__ fill,
                          int* __restrict__ col, float* __restrict__ val) {
    int e = blockIdx.x * 256 + threadIdx.x;
    if (e < E_) {
        int s = src[e], d = dst[e];
        int pos = offs[d] + atomicAdd(fill + d, 1);
        col[pos] = s;
        val[pos] = -dinv[s] * ew[e] * dinv[d];
    }
}

// ---------------------------------------------------------------- transposes
// x:[B,N,C] -> h:[N,B,C]   (writes fully coalesced, reads in 256B chunks)
__global__ void transpose_in_k(const float* __restrict__ x, float* __restrict__ h) {
    int idx = blockIdx.x * 256 + threadIdx.x;   // over N*B*16 float4
    int c4 = idx & 15;
    int nb = idx >> 4;        // n*B + b
    int b  = nb & (B_ - 1);
    int n  = nb >> 4;
    const float4 v = *(const float4*)(x + ((size_t)b * N_ + n) * C_ + (c4 << 2));
    *(float4*)(h + (size_t)nb * C_ + (c4 << 2)) = v;
}

// h:[N,B,C] -> out:[B,N,C]  (reads fully coalesced, writes in 256B chunks)
__global__ void transpose_out_k(const float* __restrict__ h, float* __restrict__ out) {
    int idx = blockIdx.x * 256 + threadIdx.x;
    int c4 = idx & 15;
    int nb = idx >> 4;
    int b  = nb & (B_ - 1);
    int n  = nb >> 4;
    const float4 v = *(const float4*)(h + (size_t)nb * C_ + (c4 << 2));
    *(float4*)(out + ((size_t)b * N_ + n) * C_ + (c4 << 2)) = v;
}

// ---------------------------------------------------------------- SpMM (CSR by dst)
// out[n,:] = sum_e val[e] * in[col[e],:]  over 1024-float node rows
__global__ __launch_bounds__(256) void spmm_k(const float* __restrict__ in,
                                              float* __restrict__ out,
                                              const int* __restrict__ offs,
                                              const int* __restrict__ col,
                                              const float* __restrict__ val) {
    const int n = blockIdx.x;
    const int t = threadIdx.x;
    const int s0 = offs[n], s1 = offs[n + 1];
    float4 acc = make_float4(0.f, 0.f, 0.f, 0.f);
    int i = s0;
    for (; i + 1 < s1; i += 2) {
        int   c0 = col[i],     c1 = col[i + 1];
        float w0 = val[i],     w1 = val[i + 1];
        const float4 v0 = *(const float4*)(in + (size_t)c0 * ROW_ + (t << 2));
        const float4 v1 = *(const float4*)(in + (size_t)c1 * ROW_ + (t << 2));
        acc.x += w0 * v0.x + w1 * v1.x;
        acc.y += w0 * v0.y + w1 * v1.y;
        acc.z += w0 * v0.z + w1 * v1.z;
        acc.w += w0 * v0.w + w1 * v1.w;
    }
    if (i < s1) {
        int c0 = col[i]; float w0 = val[i];
        const float4 v0 = *(const float4*)(in + (size_t)c0 * ROW_ + (t << 2));
        acc.x += w0 * v0.x; acc.y += w0 * v0.y; acc.z += w0 * v0.z; acc.w += w0 * v0.w;
    }
    *(float4*)(out + (size_t)n * ROW_ + (t << 2)) = acc;
}

// ---------------------------------------------------------------- combined Cheb weight
// Wc[192][128]: rows 0..63 = W0 - W2, 64..127 = W1, 128..191 = 2*W2
__global__ void wcomb_k(const float* __restrict__ cw, float* __restrict__ Wc) {
    int i = blockIdx.x * 256 + threadIdx.x;   // i < C*DIM = 8192
    if (i < C_ * DIM_) {
        float w0 = cw[i];
        float w1 = cw[C_ * DIM_ + i];
        float w2 = cw[2 * C_ * DIM_ + i];
        Wc[i]                = w0 - w2;
        Wc[C_ * DIM_ + i]    = w1;
        Wc[2 * C_ * DIM_ + i] = 2.f * w2;
    }
}

// ---------------------------------------------------------------- fused MLP block
#define FMA16(a, wbase) do {                                             \
    const float4* wp_ = (const float4*)(wbase);                          \
    float4 q0 = wp_[0], q1 = wp_[1], q2 = wp_[2], q3 = wp_[3];           \
    acc[0]  += (a) * q0.x; acc[1]  += (a) * q0.y;                        \
    acc[2]  += (a) * q0.z; acc[3]  += (a) * q0.w;                        \
    acc[4]  += (a) * q1.x; acc[5]  += (a) * q1.y;                        \
    acc[6]  += (a) * q1.z; acc[7]  += (a) * q1.w;                        \
    acc[8]  += (a) * q2.x; acc[9]  += (a) * q2.y;                        \
    acc[10] += (a) * q2.z; acc[11] += (a) * q2.w;                        \
    acc[12] += (a) * q3.x; acc[13] += (a) * q3.y;                        \
    acc[14] += (a) * q3.z; acc[15] += (a) * q3.w;                        \
} while (0)

__global__ __launch_bounds__(256) void mlp_k(
        float* __restrict__ h, const float* __restrict__ t1f, const float* __restrict__ sf,
        const float* __restrict__ Wc, const float* __restrict__ cbias,
        const float* __restrict__ w1, const float* __restrict__ b1,
        const float* __restrict__ w2, const float* __restrict__ b2,
        const float* __restrict__ betap) {
    __shared__ float inA[TM_ * LDA_];   // cols 0..191: [t0|t1|s]; later cols 64..191 reused for g2
    __shared__ float g1s[TM_ * LDG_];

    const int tid = threadIdx.x;
    const size_t row0 = (size_t)blockIdx.x * TM_;

    // stage 0: load 32 rows x 192 inputs (as 48 float4 each)
    for (int idx = tid; idx < TM_ * 48; idx += 256) {
        int r = idx / 48, c4 = idx % 48;
        size_t grow = row0 + r;
        const float* srcp;
        if (c4 < 16)      srcp = h   + grow * C_ + (c4 << 2);
        else if (c4 < 32) srcp = t1f + grow * C_ + ((c4 - 16) << 2);
        else              srcp = sf  + grow * C_ + ((c4 - 32) << 2);
        *(float4*)&inA[r * LDA_ + (c4 << 2)] = *(const float4*)srcp;
    }
    __syncthreads();

    const int r  = tid >> 3;     // 0..31
    const int l8 = tid & 7;      // 0..7
    const int d0 = l8 << 4;      // 16 outputs per thread (stages 1,2)
    const float sp    = __logf(1.f + __expf(betap[0]));   // softplus(beta)
    const float inv11 = 1.0f / 1.1f;
    float* in_r = &inA[r * LDA_];
    float* g_r  = &g1s[r * LDG_];

    // ---- stage 1: out = [t0|t1|s] @ Wc + cheb_b ; swish -> g1
    float acc[16];
#pragma unroll
    for (int j = 0; j < 16; ++j) acc[j] = cbias[d0 + j];
#pragma unroll 2
    for (int c = 0; c < 3 * C_; ++c) {
        float a = in_r[c];
        FMA16(a, Wc + c * DIM_ + d0);
    }
#pragma unroll
    for (int j = 0; j < 16; ++j) {
        float o = acc[j];
        g_r[d0 + j] = o * (1.f / (1.f + __expf(-o * sp))) * inv11;
    }
    __syncthreads();

    // ---- stage 2: g1 @ w1 + b1 ; swish -> g2 (stored into inA cols 64..191)
#pragma unroll
    for (int j = 0; j < 16; ++j) acc[j] = b1[d0 + j];
#pragma unroll 2
    for (int c = 0; c < DIM_; ++c) {
        float a = g_r[c];
        FMA16(a, w1 + c * DIM_ + d0);
    }
#pragma unroll
    for (int j = 0; j < 16; ++j) {
        float o = acc[j];
        in_r[64 + d0 + j] = o * (1.f / (1.f + __expf(-o * sp))) * inv11;
    }
    __syncthreads();

    // ---- stage 3: f = g2 @ w2 + b2 ; h += f
    const int e0 = l8 << 3;      // 8 outputs per thread
    float f[8];
#pragma unroll
    for (int j = 0; j < 8; ++j) f[j] = b2[e0 + j];
#pragma unroll 2
    for (int c = 0; c < DIM_; ++c) {
        float a = in_r[64 + c];
        const float4* wp = (const float4*)(w2 + c * C_ + e0);
        float4 q0 = wp[0], q1 = wp[1];
        f[0] += a * q0.x; f[1] += a * q0.y; f[2] += a * q0.z; f[3] += a * q0.w;
        f[4] += a * q1.x; f[5] += a * q1.y; f[6] += a * q1.z; f[7] += a * q1.w;
    }
    size_t grow = row0 + r;
    float* hp = h + grow * C_ + e0;
    float4 h0 = *(float4*)hp, h1 = *(float4*)(hp + 4);
    h0.x += f[0]; h0.y += f[1]; h0.z += f[2]; h0.w += f[3];
    h1.x += f[4]; h1.y += f[5]; h1.z += f[6]; h1.w += f[7];
    *(float4*)hp = h0;
    *(float4*)(hp + 4) = h1;
}

// ---------------------------------------------------------------- launch
extern "C" void kernel_launch(void* const* d_in, const int* in_sizes, int n_in,
                              void* d_out, int out_size, void* d_ws, size_t ws_size,
                              hipStream_t stream) {
    const float* x    = (const float*)d_in[0];
    const int*   ei   = (const int*)d_in[1];      // [2,E]: src then dst
    const float* ew   = (const float*)d_in[2];
    const float* cw   = (const float*)d_in[3];    // [NB,K,C,DIM]
    const float* cb   = (const float*)d_in[4];    // [NB,DIM]
    const float* beta = (const float*)d_in[5];    // [NB]
    const float* w1   = (const float*)d_in[6];    // [NB,DIM,DIM]
    const float* b1   = (const float*)d_in[7];    // [NB,DIM]
    const float* w2   = (const float*)d_in[8];    // [NB,DIM,C]
    const float* b2   = (const float*)d_in[9];    // [NB,C]
    float* out = (float*)d_out;

    char* ws = (char*)d_ws;
    float* h_t  = (float*)(ws + OFF_H);
    float* t1   = (float*)(ws + OFF_T1);
    float* s    = (float*)(ws + OFF_S);
    float* deg  = (float*)(ws + OFF_DEG);   // becomes dinv in place
    int*   cnt  = (int*)  (ws + OFF_CNT);
    int*   offs = (int*)  (ws + OFF_OFFS);
    int*   col  = (int*)  (ws + OFF_COL);
    float* val  = (float*)(ws + OFF_VAL);
    float* Wc   = (float*)(ws + OFF_WC);

    const int* srcI = ei;
    const int* dstI = ei + E_;

    // graph prep
    hipMemsetAsync(deg, 0, (size_t)N_ * 4, stream);
    hipMemsetAsync(cnt, 0, (size_t)N_ * 4, stream);
    deg_cnt_k<<<(E_ + 255) / 256, 256, 0, stream>>>(srcI, dstI, ew, deg, cnt);
    dinv_k<<<(N_ + 255) / 256, 256, 0, stream>>>(deg);
    scan_k<<<1, 1024, 0, stream>>>(cnt, offs);
    hipMemsetAsync(cnt, 0, (size_t)N_ * 4, stream);
    scatter_k<<<(E_ + 255) / 256, 256, 0, stream>>>(srcI, dstI, ew, deg, offs, cnt, col, val);

    // x -> [N,B,C]
    transpose_in_k<<<(N_ * B_ * 16) / 256, 256, 0, stream>>>(x, h_t);

    for (int b = 0; b < NB_; ++b) {
        wcomb_k<<<(C_ * DIM_ + 255) / 256, 256, 0, stream>>>(cw + (size_t)b * K_ * C_ * DIM_, Wc);
        spmm_k<<<N_, 256, 0, stream>>>(h_t, t1, offs, col, val);
        spmm_k<<<N_, 256, 0, stream>>>(t1, s, offs, col, val);
        mlp_k<<<NR_ / TM_, 256, 0, stream>>>(h_t, t1, s, Wc,
                                             cb + (size_t)b * DIM_,
                                             w1 + (size_t)b * DIM_ * DIM_,
                                             b1 + (size_t)b * DIM_,
                                             w2 + (size_t)b * DIM_ * C_,
                                             b2 + (size_t)b * C_,
                                             beta + b);
    }

    // [N,B,C] -> out
    transpose_out_k<<<(N_ * B_ * 16) / 256, 256, 0, stream>>>(h_t, out);
}

// Round 2
// 3216.120 us; speedup vs baseline: 3.6456x; 3.6456x over previous
//
#include <hip/hip_runtime.h>

// ---------------------------------------------------------------- constants
namespace {
constexpr int   B_   = 16;
constexpr int   N_   = 20000;
constexpr int   C_   = 64;
constexpr int   DIM_ = 128;
constexpr int   K_   = 3;
constexpr int   E_   = 640000;
constexpr int   NB_  = 3;
constexpr int   ROW_ = B_ * C_;      // 1024 floats per node row in [N,B,C]
constexpr int   NR_  = N_ * B_;      // 320000 (n*B+b) rows of C floats

constexpr int   LDK2 = 152;          // LDS k-stride (bf16) for g1/g2 tiles; 304B row stride (16B-aligned)

// bf16 weight region sizes (elements)
constexpr int   SZ1_ = 128 * 192;    // Wc^T  per block
constexpr int   SZ2_ = 128 * 128;    // w1^T  per block
constexpr int   SZ3_ = 64 * 128;     // w2^T  per block
constexpr int   SZB_ = SZ1_ + SZ2_ + SZ3_;    // 49152
constexpr int   WTOT_ = NB_ * SZB_;           // 147456

// workspace layout (bytes)
constexpr size_t SZH_     = (size_t)N_ * B_ * C_ * sizeof(float);   // 81,920,000
constexpr size_t OFF_H    = 0;
constexpr size_t OFF_T1   = SZH_;
constexpr size_t OFF_S    = 2 * SZH_;
constexpr size_t OFF_DEG  = 3 * SZH_;
constexpr size_t OFF_CNT  = OFF_DEG + (size_t)N_ * 4;
constexpr size_t OFF_OFFS = OFF_CNT + (size_t)N_ * 4;
constexpr size_t OFF_COL  = ((OFF_OFFS + (size_t)(N_ + 1) * 4 + 255) / 256) * 256;
constexpr size_t OFF_VAL  = OFF_COL + (size_t)E_ * 4;
constexpr size_t OFF_WTC  = OFF_VAL + (size_t)E_ * 4;               // bf16 Wc^T  [NB][128][192]
constexpr size_t OFF_WT1  = OFF_WTC + (size_t)NB_ * SZ1_ * 2;       // bf16 w1^T  [NB][128][128]
constexpr size_t OFF_WT2  = OFF_WT1 + (size_t)NB_ * SZ2_ * 2;       // bf16 w2^T  [NB][64][128]
} // namespace

typedef short s16x8 __attribute__((ext_vector_type(8)));
typedef float f32x4 __attribute__((ext_vector_type(4)));

// fp32 -> bf16 round-to-nearest-even (bit trick)
__device__ __forceinline__ unsigned bfr(float x) {
    unsigned u = __float_as_uint(x);
    return (u + 0x7FFFu + ((u >> 16) & 1u)) >> 16;
}
__device__ __forceinline__ unsigned pack_bf2(float x, float y) {
    return bfr(x) | (bfr(y) << 16);
}
__device__ __forceinline__ s16x8 pack8(float4 a0, float4 a1) {
    union { s16x8 v; unsigned u[4]; } r;
    r.u[0] = pack_bf2(a0.x, a0.y);
    r.u[1] = pack_bf2(a0.z, a0.w);
    r.u[2] = pack_bf2(a1.x, a1.y);
    r.u[3] = pack_bf2(a1.z, a1.w);
    return r.v;
}

// ---------------------------------------------------------------- graph prep
__global__ void deg_cnt_k(const int* __restrict__ src, const int* __restrict__ dst,
                          const float* __restrict__ ew,
                          float* __restrict__ deg, int* __restrict__ cnt) {
    int e = blockIdx.x * 256 + threadIdx.x;
    if (e < E_) {
        atomicAdd(deg + src[e], ew[e]);
        atomicAdd(cnt + dst[e], 1);
    }
}

__global__ void dinv_k(float* __restrict__ deg) {
    int i = blockIdx.x * 256 + threadIdx.x;
    if (i < N_) {
        float d = deg[i];
        deg[i] = (d > 0.f) ? rsqrtf(fmaxf(d, 1e-12f)) : 0.f;
    }
}

__global__ __launch_bounds__(1024) void scan_k(const int* __restrict__ cnt,
                                               int* __restrict__ offs) {
    __shared__ int sums[1024];
    const int tid = threadIdx.x;
    constexpr int CH = (N_ + 1023) / 1024;   // 20
    const int base = tid * CH;
    int local = 0;
    for (int j = 0; j < CH; ++j) {
        int i = base + j;
        if (i < N_) local += cnt[i];
    }
    sums[tid] = local;
    __syncthreads();
    for (int off = 1; off < 1024; off <<= 1) {
        int v = sums[tid];
        int u = (tid >= off) ? sums[tid - off] : 0;
        __syncthreads();
        sums[tid] = v + u;
        __syncthreads();
    }
    int run = (tid > 0) ? sums[tid - 1] : 0;
    for (int j = 0; j < CH; ++j) {
        int i = base + j;
        if (i < N_) { offs[i] = run; run += cnt[i]; }
    }
    if (tid == 1023) offs[N_] = sums[1023];
}

__global__ void scatter_k(const int* __restrict__ src, const int* __restrict__ dst,
                          const float* __restrict__ ew, const float* __restrict__ dinv,
                          const int* __restrict__ offs, int* __restrict__ fill,
                          int* __restrict__ col, float* __restrict__ val) {
    int e = blockIdx.x * 256 + threadIdx.x;
    if (e < E_) {
        int s = src[e], d = dst[e];
        int pos = offs[d] + atomicAdd(fill + d, 1);
        col[pos] = s;
        val[pos] = -dinv[s] * ew[e] * dinv[d];
    }
}

// ---------------------------------------------------------------- bf16 weight prep
// Wc^T[n][k]: k<64 -> W0-W2, 64..127 -> W1, 128..191 -> 2*W2 (k index = part*64 + c)
// w1^T[n][k] = w1[k][n];  w2^T[n][k] = w2[k][n]
__global__ void wprep_k(const float* __restrict__ cw, const float* __restrict__ w1,
                        const float* __restrict__ w2,
                        short* __restrict__ wtc, short* __restrict__ wt1,
                        short* __restrict__ wt2) {
    int idx = blockIdx.x * 256 + threadIdx.x;
    if (idx >= WTOT_) return;
    int b = idx / SZB_;
    int rem = idx - b * SZB_;
    if (rem < SZ1_) {
        int n = rem / 192, k = rem - n * 192;
        int part = k >> 6, c = k & 63;
        const float* base = cw + (size_t)b * 3 * 64 * 128;
        float v;
        if (part == 0)      v = base[c * 128 + n] - base[16384 + c * 128 + n];
        else if (part == 1) v = base[8192 + c * 128 + n];
        else                v = 2.f * base[16384 + c * 128 + n];
        wtc[(size_t)b * SZ1_ + n * 192 + k] = (short)bfr(v);
    } else if (rem < SZ1_ + SZ2_) {
        int r2 = rem - SZ1_;
        int n = r2 >> 7, k = r2 & 127;
        float v = w1[(size_t)b * 16384 + k * 128 + n];
        wt1[(size_t)b * SZ2_ + n * 128 + k] = (short)bfr(v);
    } else {
        int r3 = rem - SZ1_ - SZ2_;
        int n = r3 >> 7, k = r3 & 127;
        float v = w2[(size_t)b * 8192 + k * 64 + n];
        wt2[(size_t)b * SZ3_ + n * 128 + k] = (short)bfr(v);
    }
}

// ---------------------------------------------------------------- transposes
__global__ void transpose_in_k(const float* __restrict__ x, float* __restrict__ h) {
    int idx = blockIdx.x * 256 + threadIdx.x;   // over N*B*16 float4
    int c4 = idx & 15;
    int nb = idx >> 4;        // n*B + b
    int b  = nb & (B_ - 1);
    int n  = nb >> 4;
    const float4 v = *(const float4*)(x + ((size_t)b * N_ + n) * C_ + (c4 << 2));
    *(float4*)(h + (size_t)nb * C_ + (c4 << 2)) = v;
}

__global__ void transpose_out_k(const float* __restrict__ h, float* __restrict__ out) {
    int idx = blockIdx.x * 256 + threadIdx.x;
    int c4 = idx & 15;
    int nb = idx >> 4;
    int b  = nb & (B_ - 1);
    int n  = nb >> 4;
    const float4 v = *(const float4*)(h + (size_t)nb * C_ + (c4 << 2));
    *(float4*)(out + ((size_t)b * N_ + n) * C_ + (c4 << 2)) = v;
}

// ---------------------------------------------------------------- SpMM (CSR by dst)
__global__ __launch_bounds__(256) void spmm_k(const float* __restrict__ in,
                                              float* __restrict__ out,
                                              const int* __restrict__ offs,
                                              const int* __restrict__ col,
                                              const float* __restrict__ val) {
    const int n = blockIdx.x;
    const int t = threadIdx.x;
    const int s0 = offs[n], s1 = offs[n + 1];
    float4 acc = make_float4(0.f, 0.f, 0.f, 0.f);
    int i = s0;
    for (; i + 1 < s1; i += 2) {
        int   c0 = col[i],     c1 = col[i + 1];
        float w0 = val[i],     w1 = val[i + 1];
        const float4 v0 = *(const float4*)(in + (size_t)c0 * ROW_ + (t << 2));
        const float4 v1 = *(const float4*)(in + (size_t)c1 * ROW_ + (t << 2));
        acc.x += w0 * v0.x + w1 * v1.x;
        acc.y += w0 * v0.y + w1 * v1.y;
        acc.z += w0 * v0.z + w1 * v1.z;
        acc.w += w0 * v0.w + w1 * v1.w;
    }
    if (i < s1) {
        int c0 = col[i]; float w0 = val[i];
        const float4 v0 = *(const float4*)(in + (size_t)c0 * ROW_ + (t << 2));
        acc.x += w0 * v0.x; acc.y += w0 * v0.y; acc.z += w0 * v0.z; acc.w += w0 * v0.w;
    }
    *(float4*)(out + (size_t)n * ROW_ + (t << 2)) = acc;
}

// ---------------------------------------------------------------- MFMA MLP block
// WG = 256 thr = 4 waves, 64 rows (16 rows/wave). 16x16x32 bf16 MFMA, fp32 acc.
// A layout: lane holds A[m=lane&15][k=(lane>>4)*8 + j]
// B layout: lane holds B[k=(lane>>4)*8 + j][n=lane&15]  (weights stored n-major, k-contig)
// C/D:      lane holds D[row=(lane>>4)*4 + r][col=lane&15]
__global__ __launch_bounds__(256, 4) void mlp_mfma_k(
        float* __restrict__ h, const float* __restrict__ t1f, const float* __restrict__ sf,
        const short* __restrict__ wtc, const short* __restrict__ wt1,
        const short* __restrict__ wt2,
        const float* __restrict__ cbias, const float* __restrict__ b1,
        const float* __restrict__ b2, const float* __restrict__ betap) {
    __shared__ short g1s[64 * LDK2];
    __shared__ short g2s[64 * LDK2];

    const int tid  = threadIdx.x;
    const int wv   = tid >> 6;
    const int lane = tid & 63;
    const int m    = lane & 15;
    const int q    = lane >> 4;
    const int row0 = blockIdx.x * 64;
    const int rloc = wv << 4;                       // wave's row offset in tile
    const size_t growA = (size_t)(row0 + rloc + m); // this lane's A-row
    const float sp    = __logf(1.f + __expf(betap[0]));
    const float inv11 = 1.0f / 1.1f;

    // ---- stage 1: [t0|t1|s](192) @ Wc^T -> 128, swish -> g1s
    f32x4 acc[8];
#pragma unroll
    for (int t = 0; t < 8; ++t) acc[t] = (f32x4){0.f, 0.f, 0.f, 0.f};
    const float* srcs[3] = { h, t1f, sf };
#pragma unroll
    for (int kb = 0; kb < 6; ++kb) {
        const float* ap = srcs[kb >> 1] + growA * C_ + ((kb & 1) << 5) + (q << 3);
        float4 a0 = *(const float4*)ap;
        float4 a1 = *(const float4*)(ap + 4);
        s16x8 af = pack8(a0, a1);
#pragma unroll
        for (int t = 0; t < 8; ++t) {
            s16x8 bf = *(const s16x8*)(wtc + ((t << 4) + m) * 192 + (kb << 5) + (q << 3));
            acc[t] = __builtin_amdgcn_mfma_f32_16x16x32_bf16(af, bf, acc[t], 0, 0, 0);
        }
    }
#pragma unroll
    for (int t = 0; t < 8; ++t) {
        float bv = cbias[(t << 4) + m];
#pragma unroll
        for (int r = 0; r < 4; ++r) {
            float o = acc[t][r] + bv;
            float g = o * (1.f / (1.f + __expf(-o * sp))) * inv11;
            g1s[(rloc + (q << 2) + r) * LDK2 + (t << 4) + m] = (short)bfr(g);
        }
    }
    // no __syncthreads: g1/g2 dataflow is wave-private (each wave owns its 16 rows)

    // ---- stage 2: g1(128) @ w1^T -> 128, swish -> g2s
    f32x4 acc2[8];
#pragma unroll
    for (int t = 0; t < 8; ++t) acc2[t] = (f32x4){0.f, 0.f, 0.f, 0.f};
#pragma unroll
    for (int k0 = 0; k0 < 128; k0 += 32) {
        s16x8 af = *(const s16x8*)&g1s[(rloc + m) * LDK2 + k0 + (q << 3)];
#pragma unroll
        for (int t = 0; t < 8; ++t) {
            s16x8 bf = *(const s16x8*)(wt1 + (((t << 4) + m) << 7) + k0 + (q << 3));
            acc2[t] = __builtin_amdgcn_mfma_f32_16x16x32_bf16(af, bf, acc2[t], 0, 0, 0);
        }
    }
#pragma unroll
    for (int t = 0; t < 8; ++t) {
        float bv = b1[(t << 4) + m];
#pragma unroll
        for (int r = 0; r < 4; ++r) {
            float o = acc2[t][r] + bv;
            float g = o * (1.f / (1.f + __expf(-o * sp))) * inv11;
            g2s[(rloc + (q << 2) + r) * LDK2 + (t << 4) + m] = (short)bfr(g);
        }
    }

    // ---- stage 3: g2(128) @ w2^T -> 64, h += f (residual fused)
    f32x4 acc3[4];
#pragma unroll
    for (int t = 0; t < 4; ++t) acc3[t] = (f32x4){0.f, 0.f, 0.f, 0.f};
#pragma unroll
    for (int k0 = 0; k0 < 128; k0 += 32) {
        s16x8 af = *(const s16x8*)&g2s[(rloc + m) * LDK2 + k0 + (q << 3)];
#pragma unroll
        for (int t = 0; t < 4; ++t) {
            s16x8 bf = *(const s16x8*)(wt2 + (((t << 4) + m) << 7) + k0 + (q << 3));
            acc3[t] = __builtin_amdgcn_mfma_f32_16x16x32_bf16(af, bf, acc3[t], 0, 0, 0);
        }
    }
#pragma unroll
    for (int t = 0; t < 4; ++t) {
        float bv = b2[(t << 4) + m];
#pragma unroll
        for (int r = 0; r < 4; ++r) {
            float f = acc3[t][r] + bv;
            float* hp = h + (size_t)(row0 + rloc + (q << 2) + r) * C_ + (t << 4) + m;
            *hp += f;
        }
    }
}

// ---------------------------------------------------------------- launch
extern "C" void kernel_launch(void* const* d_in, const int* in_sizes, int n_in,
                              void* d_out, int out_size, void* d_ws, size_t ws_size,
                              hipStream_t stream) {
    const float* x    = (const float*)d_in[0];
    const int*   ei   = (const int*)d_in[1];      // [2,E]: src then dst
    const float* ew   = (const float*)d_in[2];
    const float* cw   = (const float*)d_in[3];    // [NB,K,C,DIM]
    const float* cb   = (const float*)d_in[4];    // [NB,DIM]
    const float* beta = (const float*)d_in[5];    // [NB]
    const float* w1   = (const float*)d_in[6];    // [NB,DIM,DIM]
    const float* b1   = (const float*)d_in[7];    // [NB,DIM]
    const float* w2   = (const float*)d_in[8];    // [NB,DIM,C]
    const float* b2   = (const float*)d_in[9];    // [NB,C]
    float* out = (float*)d_out;

    char* ws = (char*)d_ws;
    float* h_t  = (float*)(ws + OFF_H);
    float* t1   = (float*)(ws + OFF_T1);
    float* s    = (float*)(ws + OFF_S);
    float* deg  = (float*)(ws + OFF_DEG);   // becomes dinv in place
    int*   cnt  = (int*)  (ws + OFF_CNT);
    int*   offs = (int*)  (ws + OFF_OFFS);
    int*   col  = (int*)  (ws + OFF_COL);
    float* val  = (float*)(ws + OFF_VAL);
    short* wtc  = (short*)(ws + OFF_WTC);
    short* wt1  = (short*)(ws + OFF_WT1);
    short* wt2  = (short*)(ws + OFF_WT2);

    const int* srcI = ei;
    const int* dstI = ei + E_;

    // graph prep
    hipMemsetAsync(deg, 0, (size_t)N_ * 4, stream);
    hipMemsetAsync(cnt, 0, (size_t)N_ * 4, stream);
    deg_cnt_k<<<(E_ + 255) / 256, 256, 0, stream>>>(srcI, dstI, ew, deg, cnt);
    dinv_k<<<(N_ + 255) / 256, 256, 0, stream>>>(deg);
    scan_k<<<1, 1024, 0, stream>>>(cnt, offs);
    hipMemsetAsync(cnt, 0, (size_t)N_ * 4, stream);
    scatter_k<<<(E_ + 255) / 256, 256, 0, stream>>>(srcI, dstI, ew, deg, offs, cnt, col, val);

    // bf16 weights (all blocks)
    wprep_k<<<(WTOT_ + 255) / 256, 256, 0, stream>>>(cw, w1, w2, wtc, wt1, wt2);

    // x -> [N,B,C]
    transpose_in_k<<<(N_ * B_ * 16) / 256, 256, 0, stream>>>(x, h_t);

    for (int b = 0; b < NB_; ++b) {
        spmm_k<<<N_, 256, 0, stream>>>(h_t, t1, offs, col, val);
        spmm_k<<<N_, 256, 0, stream>>>(t1, s, offs, col, val);
        mlp_mfma_k<<<NR_ / 64, 256, 0, stream>>>(h_t, t1, s,
                                                 wtc + (size_t)b * SZ1_,
                                                 wt1 + (size_t)b * SZ2_,
                                                 wt2 + (size_t)b * SZ3_,
                                                 cb + (size_t)b * DIM_,
                                                 b1 + (size_t)b * DIM_,
                                                 b2 + (size_t)b * C_,
                                                 beta + b);
    }

    // [N,B,C] -> out
    transpose_out_k<<<(N_ * B_ * 16) / 256, 256, 0, stream>>>(h_t, out);
}

// Round 3
// 2059.285 us; speedup vs baseline: 5.6935x; 1.5618x over previous
//
#include <hip/hip_runtime.h>

// ---------------------------------------------------------------- constants
namespace {
constexpr int   B_   = 16;
constexpr int   N_   = 20000;
constexpr int   C_   = 64;
constexpr int   DIM_ = 128;
constexpr int   E_   = 640000;
constexpr int   NB_  = 3;
constexpr int   ROW_ = B_ * C_;      // 1024 elements per node row in [N,B,C]
constexpr int   NR_  = N_ * B_;      // 320000 (n*B+b) rows of C elements

constexpr int   LDK2 = 152;          // LDS k-stride (bf16) for g1/g2 tiles; 304B row stride

// bf16 weight region sizes (elements)
constexpr int   SZ1_ = 128 * 192;    // Wc^T  per block
constexpr int   SZ2_ = 128 * 128;    // w1^T  per block
constexpr int   SZ3_ = 64 * 128;     // w2^T  per block
constexpr int   SZB_ = SZ1_ + SZ2_ + SZ3_;    // 49152
constexpr int   WTOT_ = NB_ * SZB_;           // 147456

// workspace layout (bytes)
constexpr size_t SZH_  = (size_t)N_ * ROW_ * sizeof(float);   // 81,920,000 (fp32 h)
constexpr size_t SZHB_ = (size_t)N_ * ROW_ * 2;               // 40,960,000 (bf16 row image)
constexpr size_t OFF_H    = 0;
constexpr size_t OFF_HB   = SZH_;
constexpr size_t OFF_T1B  = OFF_HB  + SZHB_;
constexpr size_t OFF_SB   = OFF_T1B + SZHB_;
constexpr size_t OFF_DEG  = OFF_SB  + SZHB_;
constexpr size_t OFF_CNT  = OFF_DEG + (size_t)N_ * 4;
constexpr size_t OFF_OFFS = OFF_CNT + (size_t)N_ * 4;
constexpr size_t OFF_COL  = ((OFF_OFFS + (size_t)(N_ + 1) * 4 + 255) / 256) * 256;
constexpr size_t OFF_VAL  = OFF_COL + (size_t)E_ * 4;
constexpr size_t OFF_WTC  = OFF_VAL + (size_t)E_ * 4;               // bf16 Wc^T  [NB][128][192]
constexpr size_t OFF_WT1  = OFF_WTC + (size_t)NB_ * SZ1_ * 2;       // bf16 w1^T  [NB][128][128]
constexpr size_t OFF_WT2  = OFF_WT1 + (size_t)NB_ * SZ2_ * 2;       // bf16 w2^T  [NB][64][128]
// total ~210 MB
} // namespace

typedef short s16x8 __attribute__((ext_vector_type(8)));
typedef float f32x4 __attribute__((ext_vector_type(4)));
typedef unsigned int u32;

// fp32 -> bf16 round-to-nearest-even (bit trick)
__device__ __forceinline__ u32 bfr(float x) {
    u32 u = __float_as_uint(x);
    return (u + 0x7FFFu + ((u >> 16) & 1u)) >> 16;
}
__device__ __forceinline__ u32 pack_bf2(float x, float y) {
    return bfr(x) | (bfr(y) << 16);
}
__device__ __forceinline__ float bflo(u32 u) { return __uint_as_float(u << 16); }
__device__ __forceinline__ float bfhi(u32 u) { return __uint_as_float(u & 0xFFFF0000u); }

// ---------------------------------------------------------------- graph prep
__global__ void deg_cnt_k(const int* __restrict__ src, const int* __restrict__ dst,
                          const float* __restrict__ ew,
                          float* __restrict__ deg, int* __restrict__ cnt) {
    int e = blockIdx.x * 256 + threadIdx.x;
    if (e < E_) {
        atomicAdd(deg + src[e], ew[e]);
        atomicAdd(cnt + dst[e], 1);
    }
}

__global__ void dinv_k(float* __restrict__ deg) {
    int i = blockIdx.x * 256 + threadIdx.x;
    if (i < N_) {
        float d = deg[i];
        deg[i] = (d > 0.f) ? rsqrtf(fmaxf(d, 1e-12f)) : 0.f;
    }
}

__global__ __launch_bounds__(1024) void scan_k(const int* __restrict__ cnt,
                                               int* __restrict__ offs) {
    __shared__ int sums[1024];
    const int tid = threadIdx.x;
    constexpr int CH = (N_ + 1023) / 1024;   // 20
    const int base = tid * CH;
    int local = 0;
    for (int j = 0; j < CH; ++j) {
        int i = base + j;
        if (i < N_) local += cnt[i];
    }
    sums[tid] = local;
    __syncthreads();
    for (int off = 1; off < 1024; off <<= 1) {
        int v = sums[tid];
        int u = (tid >= off) ? sums[tid - off] : 0;
        __syncthreads();
        sums[tid] = v + u;
        __syncthreads();
    }
    int run = (tid > 0) ? sums[tid - 1] : 0;
    for (int j = 0; j < CH; ++j) {
        int i = base + j;
        if (i < N_) { offs[i] = run; run += cnt[i]; }
    }
    if (tid == 1023) offs[N_] = sums[1023];
}

__global__ void scatter_k(const int* __restrict__ src, const int* __restrict__ dst,
                          const float* __restrict__ ew, const float* __restrict__ dinv,
                          const int* __restrict__ offs, int* __restrict__ fill,
                          int* __restrict__ col, float* __restrict__ val) {
    int e = blockIdx.x * 256 + threadIdx.x;
    if (e < E_) {
        int s = src[e], d = dst[e];
        int pos = offs[d] + atomicAdd(fill + d, 1);
        col[pos] = s;
        val[pos] = -dinv[s] * ew[e] * dinv[d];
    }
}

// ---------------------------------------------------------------- bf16 weight prep
__global__ void wprep_k(const float* __restrict__ cw, const float* __restrict__ w1,
                        const float* __restrict__ w2,
                        short* __restrict__ wtc, short* __restrict__ wt1,
                        short* __restrict__ wt2) {
    int idx = blockIdx.x * 256 + threadIdx.x;
    if (idx >= WTOT_) return;
    int b = idx / SZB_;
    int rem = idx - b * SZB_;
    if (rem < SZ1_) {
        int n = rem / 192, k = rem - n * 192;
        int part = k >> 6, c = k & 63;
        const float* base = cw + (size_t)b * 3 * 64 * 128;
        float v;
        if (part == 0)      v = base[c * 128 + n] - base[16384 + c * 128 + n];
        else if (part == 1) v = base[8192 + c * 128 + n];
        else                v = 2.f * base[16384 + c * 128 + n];
        wtc[(size_t)b * SZ1_ + n * 192 + k] = (short)bfr(v);
    } else if (rem < SZ1_ + SZ2_) {
        int r2 = rem - SZ1_;
        int n = r2 >> 7, k = r2 & 127;
        float v = w1[(size_t)b * 16384 + k * 128 + n];
        wt1[(size_t)b * SZ2_ + n * 128 + k] = (short)bfr(v);
    } else {
        int r3 = rem - SZ1_ - SZ2_;
        int n = r3 >> 7, k = r3 & 127;
        float v = w2[(size_t)b * 8192 + k * 64 + n];
        wt2[(size_t)b * SZ3_ + n * 128 + k] = (short)bfr(v);
    }
}

// ---------------------------------------------------------------- transposes
// x:[B,N,C] -> h:[N,B,C] fp32 + hb:[N,B,C] bf16
__global__ void transpose_in_k(const float* __restrict__ x, float* __restrict__ h,
                               ushort* __restrict__ hb) {
    int idx = blockIdx.x * 256 + threadIdx.x;   // over N*B*16 float4
    int c4 = idx & 15;
    int nb = idx >> 4;        // n*B + b
    int b  = nb & (B_ - 1);
    int n  = nb >> 4;
    const float4 v = *(const float4*)(x + ((size_t)b * N_ + n) * C_ + (c4 << 2));
    *(float4*)(h + (size_t)nb * C_ + (c4 << 2)) = v;
    uint2 p;
    p.x = pack_bf2(v.x, v.y);
    p.y = pack_bf2(v.z, v.w);
    *(uint2*)(hb + (size_t)nb * C_ + (c4 << 2)) = p;
}

__global__ void transpose_out_k(const float* __restrict__ h, float* __restrict__ out) {
    int idx = blockIdx.x * 256 + threadIdx.x;
    int c4 = idx & 15;
    int nb = idx >> 4;
    int b  = nb & (B_ - 1);
    int n  = nb >> 4;
    const float4 v = *(const float4*)(h + (size_t)nb * C_ + (c4 << 2));
    *(float4*)(out + ((size_t)b * N_ + n) * C_ + (c4 << 2)) = v;
}

// ---------------------------------------------------------------- SpMM (CSR by dst), bf16 rows
// out[n,:] = sum_e val[e] * in[col[e],:]; each thread owns 4 bf16 (8B) of the 2KB row
__global__ __launch_bounds__(256) void spmm_bf_k(const ushort* __restrict__ in,
                                                 ushort* __restrict__ out,
                                                 const int* __restrict__ offs,
                                                 const int* __restrict__ col,
                                                 const float* __restrict__ val) {
    const int n = blockIdx.x;
    const int t = threadIdx.x;
    const int s0 = offs[n], s1 = offs[n + 1];
    const int off4 = t << 2;
    float a0 = 0.f, a1 = 0.f, a2 = 0.f, a3 = 0.f;
    int i = s0;
    for (; i + 3 < s1; i += 4) {
        int   c0 = col[i],     c1 = col[i + 1], c2 = col[i + 2], c3 = col[i + 3];
        float w0 = val[i],     w1 = val[i + 1], w2 = val[i + 2], w3 = val[i + 3];
        uint2 v0 = *(const uint2*)(in + (size_t)c0 * ROW_ + off4);
        uint2 v1 = *(const uint2*)(in + (size_t)c1 * ROW_ + off4);
        uint2 v2 = *(const uint2*)(in + (size_t)c2 * ROW_ + off4);
        uint2 v3 = *(const uint2*)(in + (size_t)c3 * ROW_ + off4);
        a0 += w0 * bflo(v0.x) + w1 * bflo(v1.x) + w2 * bflo(v2.x) + w3 * bflo(v3.x);
        a1 += w0 * bfhi(v0.x) + w1 * bfhi(v1.x) + w2 * bfhi(v2.x) + w3 * bfhi(v3.x);
        a2 += w0 * bflo(v0.y) + w1 * bflo(v1.y) + w2 * bflo(v2.y) + w3 * bflo(v3.y);
        a3 += w0 * bfhi(v0.y) + w1 * bfhi(v1.y) + w2 * bfhi(v2.y) + w3 * bfhi(v3.y);
    }
    for (; i < s1; ++i) {
        int c0 = col[i]; float w0 = val[i];
        uint2 v0 = *(const uint2*)(in + (size_t)c0 * ROW_ + off4);
        a0 += w0 * bflo(v0.x);
        a1 += w0 * bfhi(v0.x);
        a2 += w0 * bflo(v0.y);
        a3 += w0 * bfhi(v0.y);
    }
    uint2 p;
    p.x = pack_bf2(a0, a1);
    p.y = pack_bf2(a2, a3);
    *(uint2*)(out + (size_t)n * ROW_ + off4) = p;
}

// ---------------------------------------------------------------- MFMA MLP block
// WG = 256 thr = 4 waves, 64 rows (16 rows/wave). 16x16x32 bf16 MFMA, fp32 acc.
// A layout: lane holds A[m=lane&15][k=(lane>>4)*8 + j]
// B layout: lane holds B[k=(lane>>4)*8 + j][n=lane&15]  (weights stored n-major, k-contig)
// C/D:      lane holds D[row=(lane>>4)*4 + r][col=lane&15]
__global__ __launch_bounds__(256, 4) void mlp_mfma_k(
        float* __restrict__ h, ushort* __restrict__ hb,
        const ushort* __restrict__ t1b, const ushort* __restrict__ sb,
        const short* __restrict__ wtc, const short* __restrict__ wt1,
        const short* __restrict__ wt2,
        const float* __restrict__ cbias, const float* __restrict__ b1,
        const float* __restrict__ b2, const float* __restrict__ betap) {
    __shared__ short g1s[64 * LDK2];
    __shared__ short g2s[64 * LDK2];

    const int tid  = threadIdx.x;
    const int wv   = tid >> 6;
    const int lane = tid & 63;
    const int m    = lane & 15;
    const int q    = lane >> 4;
    const int row0 = blockIdx.x * 64;
    const int rloc = wv << 4;                       // wave's row offset in tile
    const size_t growA = (size_t)(row0 + rloc + m); // this lane's A-row
    const float sp    = __logf(1.f + __expf(betap[0]));
    const float inv11 = 1.0f / 1.1f;

    // ---- stage 1: [t0|t1|s](192) @ Wc^T -> 128, swish -> g1s
    f32x4 acc[8];
#pragma unroll
    for (int t = 0; t < 8; ++t) acc[t] = (f32x4){0.f, 0.f, 0.f, 0.f};
    const ushort* srcs[3] = { hb, t1b, sb };
#pragma unroll
    for (int kb = 0; kb < 6; ++kb) {
        const ushort* ap = srcs[kb >> 1] + growA * C_ + ((kb & 1) << 5) + (q << 3);
        s16x8 af = *(const s16x8*)ap;
#pragma unroll
        for (int t = 0; t < 8; ++t) {
            s16x8 bf = *(const s16x8*)(wtc + ((t << 4) + m) * 192 + (kb << 5) + (q << 3));
            acc[t] = __builtin_amdgcn_mfma_f32_16x16x32_bf16(af, bf, acc[t], 0, 0, 0);
        }
    }
#pragma unroll
    for (int t = 0; t < 8; ++t) {
        float bv = cbias[(t << 4) + m];
#pragma unroll
        for (int r = 0; r < 4; ++r) {
            float o = acc[t][r] + bv;
            float g = o * (1.f / (1.f + __expf(-o * sp))) * inv11;
            g1s[(rloc + (q << 2) + r) * LDK2 + (t << 4) + m] = (short)bfr(g);
        }
    }
    // no __syncthreads: g1/g2 dataflow is wave-private (each wave owns its 16 rows)

    // ---- stage 2: g1(128) @ w1^T -> 128, swish -> g2s
    f32x4 acc2[8];
#pragma unroll
    for (int t = 0; t < 8; ++t) acc2[t] = (f32x4){0.f, 0.f, 0.f, 0.f};
#pragma unroll
    for (int k0 = 0; k0 < 128; k0 += 32) {
        s16x8 af = *(const s16x8*)&g1s[(rloc + m) * LDK2 + k0 + (q << 3)];
#pragma unroll
        for (int t = 0; t < 8; ++t) {
            s16x8 bf = *(const s16x8*)(wt1 + (((t << 4) + m) << 7) + k0 + (q << 3));
            acc2[t] = __builtin_amdgcn_mfma_f32_16x16x32_bf16(af, bf, acc2[t], 0, 0, 0);
        }
    }
#pragma unroll
    for (int t = 0; t < 8; ++t) {
        float bv = b1[(t << 4) + m];
#pragma unroll
        for (int r = 0; r < 4; ++r) {
            float o = acc2[t][r] + bv;
            float g = o * (1.f / (1.f + __expf(-o * sp))) * inv11;
            g2s[(rloc + (q << 2) + r) * LDK2 + (t << 4) + m] = (short)bfr(g);
        }
    }

    // ---- stage 3: g2(128) @ w2^T -> 64, h += f (residual fused), refresh hb
    f32x4 acc3[4];
#pragma unroll
    for (int t = 0; t < 4; ++t) acc3[t] = (f32x4){0.f, 0.f, 0.f, 0.f};
#pragma unroll
    for (int k0 = 0; k0 < 128; k0 += 32) {
        s16x8 af = *(const s16x8*)&g2s[(rloc + m) * LDK2 + k0 + (q << 3)];
#pragma unroll
        for (int t = 0; t < 4; ++t) {
            s16x8 bf = *(const s16x8*)(wt2 + (((t << 4) + m) << 7) + k0 + (q << 3));
            acc3[t] = __builtin_amdgcn_mfma_f32_16x16x32_bf16(af, bf, acc3[t], 0, 0, 0);
        }
    }
#pragma unroll
    for (int t = 0; t < 4; ++t) {
        float bv = b2[(t << 4) + m];
#pragma unroll
        for (int r = 0; r < 4; ++r) {
            size_t eidx = (size_t)(row0 + rloc + (q << 2) + r) * C_ + (t << 4) + m;
            float nv = h[eidx] + acc3[t][r] + bv;
            h[eidx] = nv;
            hb[eidx] = (ushort)bfr(nv);
        }
    }
}

// ---------------------------------------------------------------- launch
extern "C" void kernel_launch(void* const* d_in, const int* in_sizes, int n_in,
                              void* d_out, int out_size, void* d_ws, size_t ws_size,
                              hipStream_t stream) {
    const float* x    = (const float*)d_in[0];
    const int*   ei   = (const int*)d_in[1];      // [2,E]: src then dst
    const float* ew   = (const float*)d_in[2];
    const float* cw   = (const float*)d_in[3];    // [NB,K,C,DIM]
    const float* cb   = (const float*)d_in[4];    // [NB,DIM]
    const float* beta = (const float*)d_in[5];    // [NB]
    const float* w1   = (const float*)d_in[6];    // [NB,DIM,DIM]
    const float* b1   = (const float*)d_in[7];    // [NB,DIM]
    const float* w2   = (const float*)d_in[8];    // [NB,DIM,C]
    const float* b2   = (const float*)d_in[9];    // [NB,C]
    float* out = (float*)d_out;

    char* ws = (char*)d_ws;
    float*  h_t  = (float*) (ws + OFF_H);
    ushort* hb   = (ushort*)(ws + OFF_HB);
    ushort* t1b  = (ushort*)(ws + OFF_T1B);
    ushort* sb   = (ushort*)(ws + OFF_SB);
    float*  deg  = (float*) (ws + OFF_DEG);   // becomes dinv in place
    int*    cnt  = (int*)   (ws + OFF_CNT);
    int*    offs = (int*)   (ws + OFF_OFFS);
    int*    col  = (int*)   (ws + OFF_COL);
    float*  val  = (float*) (ws + OFF_VAL);
    short*  wtc  = (short*) (ws + OFF_WTC);
    short*  wt1  = (short*) (ws + OFF_WT1);
    short*  wt2  = (short*) (ws + OFF_WT2);

    const int* srcI = ei;
    const int* dstI = ei + E_;

    // graph prep
    hipMemsetAsync(deg, 0, (size_t)N_ * 4, stream);
    hipMemsetAsync(cnt, 0, (size_t)N_ * 4, stream);
    deg_cnt_k<<<(E_ + 255) / 256, 256, 0, stream>>>(srcI, dstI, ew, deg, cnt);
    dinv_k<<<(N_ + 255) / 256, 256, 0, stream>>>(deg);
    scan_k<<<1, 1024, 0, stream>>>(cnt, offs);
    hipMemsetAsync(cnt, 0, (size_t)N_ * 4, stream);
    scatter_k<<<(E_ + 255) / 256, 256, 0, stream>>>(srcI, dstI, ew, deg, offs, cnt, col, val);

    // bf16 weights (all blocks)
    wprep_k<<<(WTOT_ + 255) / 256, 256, 0, stream>>>(cw, w1, w2, wtc, wt1, wt2);

    // x -> [N,B,C] (fp32 + bf16 image)
    transpose_in_k<<<(N_ * B_ * 16) / 256, 256, 0, stream>>>(x, h_t, hb);

    for (int b = 0; b < NB_; ++b) {
        spmm_bf_k<<<N_, 256, 0, stream>>>(hb, t1b, offs, col, val);
        spmm_bf_k<<<N_, 256, 0, stream>>>(t1b, sb, offs, col, val);
        mlp_mfma_k<<<NR_ / 64, 256, 0, stream>>>(h_t, hb, t1b, sb,
                                                 wtc + (size_t)b * SZ1_,
                                                 wt1 + (size_t)b * SZ2_,
                                                 wt2 + (size_t)b * SZ3_,
                                                 cb + (size_t)b * DIM_,
                                                 b1 + (size_t)b * DIM_,
                                                 b2 + (size_t)b * C_,
                                                 beta + b);
    }

    // [N,B,C] -> out
    transpose_out_k<<<(N_ * B_ * 16) / 256, 256, 0, stream>>>(h_t, out);
}